// Round 1
// baseline (1098.272 us; speedup 1.0000x reference)
//
#include <hip/hip_runtime.h>
#include <hip/hip_bf16.h>

typedef __bf16 bf16_t;
typedef bf16_t bf16x8 __attribute__((ext_vector_type(8)));
typedef float f32x4 __attribute__((ext_vector_type(4)));

#define L_NUM 3
#define E_NUM 4
#define D_DIM 1024
#define R_DIM 64
#define B_ROWS 32768
#define BT 16            // rows per block (halved: enables 2 blocks/CU)
#define TPB 512
#define N1 272           // 256 V-cols + 4 gating cols + 12 zero pad
#define XL_STRIDE 1032   // 1024 + 8 pad (2064B row -> 2-way bank alias, free)
#define T1_STRIDE 264    // 256 + 8 pad (528B row -> 2-way bank alias, free)

#define VT_ELEMS (L_NUM * N1 * D_DIM)            // 835584
#define UT_ELEMS (L_NUM * D_DIM * 256)           // 786432
#define CB_ELEMS (L_NUM * E_NUM * R_DIM * R_DIM) // 49152

#define MFMA16(a, b, c) __builtin_amdgcn_mfma_f32_16x16x32_bf16((a), (b), (c), 0, 0, 0)

__device__ __forceinline__ ushort f2b(float f) {
  union { float f; unsigned u; } x; x.f = f;
  unsigned r = (x.u + 0x7fffu + ((x.u >> 16) & 1u)) >> 16;  // RNE
  return (ushort)r;
}
__device__ __forceinline__ float b2f(ushort h) {
  union { unsigned u; float f; } x; x.u = ((unsigned)h) << 16;
  return x.f;
}
__device__ __forceinline__ float tanh_fast(float x) {
  float cx = fminf(fmaxf(x, -15.f), 15.f);
  float e = __expf(2.f * cx);
  return (e - 1.f) / (e + 1.f);
}

// ---------------- weight prepack: f32 -> bf16, B^T ([N][K]) layouts ----------------

__global__ void pack_vt_kernel(const float* __restrict__ V, const float* __restrict__ gw,
                               ushort* __restrict__ vt) {
  int idx = blockIdx.x * 256 + threadIdx.x;
  if (idx >= VT_ELEMS) return;
  int d = idx & (D_DIM - 1);
  int n = (idx >> 10) % N1;
  int l = idx / (N1 * D_DIM);
  float val = 0.f;
  if (n < 256) {
    int e = n >> 6, r = n & 63;
    val = V[(((l * E_NUM + e) * D_DIM) + d) * R_DIM + r];   // Vt[l][e*64+r][d] = V[l,e,d,r]
  } else if (n < 260) {
    val = gw[(n - 256) * D_DIM + d];                        // gating cols
  }
  vt[idx] = f2b(val);
}

__global__ void pack_ut_kernel(const float* __restrict__ U, ushort* __restrict__ ut) {
  int idx = blockIdx.x * 256 + threadIdx.x;
  if (idx >= UT_ELEMS) return;
  int er = idx & 255;
  int d = (idx >> 8) & (D_DIM - 1);
  int l = idx >> 18;
  int e = er >> 6, r = er & 63;
  ut[idx] = f2b(U[((l * E_NUM + e) * D_DIM + d) * R_DIM + r]);  // Ut[l][d][e*64+r]
}

__global__ void pack_cb_kernel(const float* __restrict__ C, ushort* __restrict__ cb) {
  int idx = blockIdx.x * 256 + threadIdx.x;
  if (idx >= CB_ELEMS) return;
  cb[idx] = f2b(C[idx]);   // C[l,e,r,s] already is Bt[n=r][k=s]
}

// ---------------- fused 3-layer CrossNet: each block owns 16 rows end-to-end ----------------
// BT=16 halves per-block LDS (74496 B) and per-wave registers -> 2 blocks/CU (50% occupancy).
// Gating is computed redundantly per-wave in registers (shared L1-hot B-tile) and softmaxed
// via intra-wave shuffles: the serial 32-thread softmax phase + glog/gate LDS are gone.

__global__ __launch_bounds__(TPB, 4) void crossnet_fused(
    const float* __restrict__ inputs, const float* __restrict__ bias,
    const ushort* __restrict__ Vt, const ushort* __restrict__ Ut,
    const ushort* __restrict__ Cb, float* __restrict__ out) {
  __shared__ ushort xl[BT * XL_STRIDE];    // x_l bf16, A-operand for GEMM1 (33024 B)
  __shared__ ushort x0s[BT * XL_STRIDE];   // x0 bf16 (33024 B)
  __shared__ ushort t1[BT * T1_STRIDE];    // v1, later w = gate*v2 (8448 B)

  const int tid = threadIdx.x;
  const int wave = tid >> 6;
  const int lane = tid & 63;
  const int l15 = lane & 15;
  const int quad = lane >> 4;
  const long rowbase = (long)blockIdx.x * BT;

  // ---- stage inputs -> xl, x0s (coalesced float4): 16 rows x 256 float4 ----
  #pragma unroll
  for (int i = 0; i < 8; ++i) {
    int idx = tid + i * TPB;       // float4 index within [16][256]
    int r = idx >> 8;
    int c4 = idx & 255;
    float4 v = ((const float4*)(inputs + (rowbase + r) * D_DIM))[c4];
    ushort4 h;
    h.x = f2b(v.x); h.y = f2b(v.y); h.z = f2b(v.z); h.w = f2b(v.w);
    *(ushort4*)&xl[r * XL_STRIDE + c4 * 4] = h;
    *(ushort4*)&x0s[r * XL_STRIDE + c4 * 4] = h;
  }

  // ---- x_l kept in f32 registers at this wave's GEMM2 C-layout positions ----
  // wave owns cols [wave*128, wave*128+128); lane holds rows quad*4+rg, col nt*16+l15
  float xlr[8][4];
  #pragma unroll
  for (int nt = 0; nt < 8; ++nt)
    #pragma unroll
    for (int rg = 0; rg < 4; ++rg) {
      int row = quad * 4 + rg;
      int col = wave * 128 + nt * 16 + l15;
      xlr[nt][rg] = inputs[(rowbase + row) * D_DIM + col];
    }
  __syncthreads();

  const f32x4 zf = {0.f, 0.f, 0.f, 0.f};
  const int eC = wave >> 1;   // expert this wave handles in phase C
  const int nh = wave & 1;    // which 32-col half of the 64 r-outputs

  for (int l = 0; l < L_NUM; ++l) {
    const ushort* vtl = Vt + l * N1 * D_DIM;
    const ushort* utl = Ut + l * D_DIM * 256;
    const ushort* cbl = Cb + l * E_NUM * R_DIM * R_DIM;

    // ================= Phase A: GEMM1  T1[16,256] = xl[16,1024] @ V  (+ gating tile) ====
    f32x4 acc1[2];
    acc1[0] = zf; acc1[1] = zf;
    f32x4 accg = zf;   // gating logits tile (cols 256..271), redundant per wave

    const ushort* xa0 = &xl[l15 * XL_STRIDE + quad * 8];
    const ushort* vb0 = vtl + (wave * 32 + l15) * D_DIM + quad * 8;
    const ushort* vb1 = vb0 + 16 * D_DIM;
    const ushort* vbg = vtl + (256 + l15) * D_DIM + quad * 8;
    #pragma unroll 4
    for (int k0 = 0; k0 < D_DIM; k0 += 32) {
      bf16x8 a0 = *(const bf16x8*)(xa0 + k0);
      bf16x8 b0 = *(const bf16x8*)(vb0 + k0);
      bf16x8 b1 = *(const bf16x8*)(vb1 + k0);
      bf16x8 bg = *(const bf16x8*)(vbg + k0);
      acc1[0] = MFMA16(a0, b0, acc1[0]);
      acc1[1] = MFMA16(a0, b1, acc1[1]);
      accg    = MFMA16(a0, bg, accg);
    }

    // epilogue: v1 = tanh(T1) -> t1 (bf16)
    #pragma unroll
    for (int t = 0; t < 2; ++t) {
      int ncol = wave * 32 + t * 16 + l15;
      #pragma unroll
      for (int rg = 0; rg < 4; ++rg)
        t1[(quad * 4 + rg) * T1_STRIDE + ncol] = f2b(tanh_fast(acc1[t][rg]));
    }

    // in-register softmax over E=4 (lanes l15=0..3 of my quad hold the 4 logits per row)
    float gr[4];
    {
      const int qbase = lane & 48;
      #pragma unroll
      for (int rg = 0; rg < 4; ++rg) {
        float g0 = __shfl(accg[rg], qbase + 0);
        float g1 = __shfl(accg[rg], qbase + 1);
        float g2 = __shfl(accg[rg], qbase + 2);
        float g3 = __shfl(accg[rg], qbase + 3);
        float mx = fmaxf(fmaxf(g0, g1), fmaxf(g2, g3));
        float e0 = __expf(g0 - mx), e1 = __expf(g1 - mx);
        float e2 = __expf(g2 - mx), e3 = __expf(g3 - mx);
        float inv = 1.f / (e0 + e1 + e2 + e3);
        float ge = (eC == 0) ? e0 : (eC == 1) ? e1 : (eC == 2) ? e2 : e3;
        gr[rg] = ge * inv;
      }
    }
    __syncthreads();   // t1 (v1) ready for all waves

    // ================= Phase C: block-diag v2 = tanh(C @ v1), w = gate*v2 =================
    f32x4 acc2[2];
    acc2[0] = zf; acc2[1] = zf;
    #pragma unroll
    for (int k0 = 0; k0 < 64; k0 += 32) {
      bf16x8 a0 = *(const bf16x8*)&t1[l15 * T1_STRIDE + eC * 64 + k0 + quad * 8];
      bf16x8 b0 = *(const bf16x8*)&cbl[(eC * 64 + nh * 32 + l15) * 64 + k0 + quad * 8];
      bf16x8 b1 = *(const bf16x8*)&cbl[(eC * 64 + nh * 32 + 16 + l15) * 64 + k0 + quad * 8];
      acc2[0] = MFMA16(a0, b0, acc2[0]);
      acc2[1] = MFMA16(a0, b1, acc2[1]);
    }
    __syncthreads();  // all v1 reads done -> safe to overwrite t1 with w
    #pragma unroll
    for (int t = 0; t < 2; ++t) {
      int ncol = eC * 64 + nh * 32 + t * 16 + l15;
      #pragma unroll
      for (int rg = 0; rg < 4; ++rg)
        t1[(quad * 4 + rg) * T1_STRIDE + ncol] = f2b(gr[rg] * tanh_fast(acc2[t][rg]));
    }
    __syncthreads();

    // ================= Phase D: GEMM2  S[16,1024] = w[16,256] @ Ut^T =================
    f32x4 acc3[8];
    #pragma unroll
    for (int nt = 0; nt < 8; ++nt) acc3[nt] = zf;
    const ushort* wa0 = &t1[l15 * T1_STRIDE + quad * 8];
    const ushort* ub = utl + (wave * 128 + l15) * 256 + quad * 8;
    #pragma unroll 2
    for (int k0 = 0; k0 < 256; k0 += 32) {
      bf16x8 a0 = *(const bf16x8*)(wa0 + k0);
      #pragma unroll
      for (int nt = 0; nt < 8; ++nt) {
        bf16x8 b = *(const bf16x8*)(ub + nt * 16 * 256 + k0);
        acc3[nt] = MFMA16(a0, b, acc3[nt]);
      }
    }

    // epilogue: x_new = x_l + x0*(S + bias[l]); update f32 regs + bf16 LDS shadow
    #pragma unroll
    for (int nt = 0; nt < 8; ++nt) {
      int col = wave * 128 + nt * 16 + l15;
      float bv = bias[l * D_DIM + col];
      #pragma unroll
      for (int rg = 0; rg < 4; ++rg) {
        int row = quad * 4 + rg;
        float x0v = b2f(x0s[row * XL_STRIDE + col]);
        float xn = xlr[nt][rg] + x0v * (acc3[nt][rg] + bv);
        xlr[nt][rg] = xn;
        xl[row * XL_STRIDE + col] = f2b(xn);
      }
    }
    __syncthreads();  // xl/t1 safe for next layer
  }

  // ---- final store (f32 residual path, full precision) ----
  #pragma unroll
  for (int nt = 0; nt < 8; ++nt) {
    int col = wave * 128 + nt * 16 + l15;
    #pragma unroll
    for (int rg = 0; rg < 4; ++rg) {
      int row = quad * 4 + rg;
      out[(rowbase + row) * D_DIM + col] = xlr[nt][rg];
    }
  }
}

extern "C" void kernel_launch(void* const* d_in, const int* in_sizes, int n_in,
                              void* d_out, int out_size, void* d_ws, size_t ws_size,
                              hipStream_t stream) {
  (void)in_sizes; (void)n_in; (void)out_size; (void)ws_size;
  const float* inputs = (const float*)d_in[0];
  const float* U      = (const float*)d_in[1];
  const float* V      = (const float*)d_in[2];
  const float* C      = (const float*)d_in[3];
  const float* gw     = (const float*)d_in[4];
  const float* bias   = (const float*)d_in[5];
  float* out = (float*)d_out;

  ushort* vt = (ushort*)d_ws;          // 3*272*1024 bf16
  ushort* ut = vt + VT_ELEMS;          // 3*1024*256 bf16
  ushort* cb = ut + UT_ELEMS;          // 3*4*64*64  bf16

  pack_vt_kernel<<<(VT_ELEMS + 255) / 256, 256, 0, stream>>>(V, gw, vt);
  pack_ut_kernel<<<(UT_ELEMS + 255) / 256, 256, 0, stream>>>(U, ut);
  pack_cb_kernel<<<(CB_ELEMS + 255) / 256, 256, 0, stream>>>(C, cb);

  crossnet_fused<<<B_ROWS / BT, TPB, 0, stream>>>(inputs, bias, vt, ut, cb, out);
}

// Round 2
// 858.375 us; speedup vs baseline: 1.2795x; 1.2795x over previous
//
#include <hip/hip_runtime.h>
#include <hip/hip_bf16.h>

typedef __bf16 bf16_t;
typedef bf16_t bf16x8 __attribute__((ext_vector_type(8)));
typedef float f32x4 __attribute__((ext_vector_type(4)));

#define L_NUM 3
#define E_NUM 4
#define D_DIM 1024
#define R_DIM 64
#define B_ROWS 32768
#define BT 32            // rows per block (round-0 traffic profile: weight stream amortized over 32 rows)
#define TPB 1024         // 16 waves, ONE block/CU -> 4 waves/SIMD (50% occupancy) with per-thread state halved
#define N1 272           // 256 V-cols + 4 gating cols + 12 zero pad
#define XL_STRIDE 1032   // 1024 + 8 pad (2064B row -> 2-way bank alias, free)
#define T1_STRIDE 264    // 256 + 8 pad (528B row -> 2-way bank alias, free)

#define VT_ELEMS (L_NUM * N1 * D_DIM)            // 835584
#define UT_ELEMS (L_NUM * D_DIM * 256)           // 786432
#define CB_ELEMS (L_NUM * E_NUM * R_DIM * R_DIM) // 49152
#define PACK_TOTAL (VT_ELEMS + UT_ELEMS + CB_ELEMS)

#define MFMA16(a, b, c) __builtin_amdgcn_mfma_f32_16x16x32_bf16((a), (b), (c), 0, 0, 0)

__device__ __forceinline__ ushort f2b(float f) {
  union { float f; unsigned u; } x; x.f = f;
  unsigned r = (x.u + 0x7fffu + ((x.u >> 16) & 1u)) >> 16;  // RNE
  return (ushort)r;
}
__device__ __forceinline__ float b2f(ushort h) {
  union { unsigned u; float f; } x; x.u = ((unsigned)h) << 16;
  return x.f;
}
__device__ __forceinline__ float tanh_fast(float x) {
  float cx = fminf(fmaxf(x, -15.f), 15.f);
  float e = __expf(2.f * cx);
  return (e - 1.f) / (e + 1.f);
}

// ---------------- weight prepack (single launch): f32 -> bf16, B^T ([N][K]) layouts ----------------

__global__ void pack_all_kernel(const float* __restrict__ U, const float* __restrict__ V,
                                const float* __restrict__ C, const float* __restrict__ gw,
                                ushort* __restrict__ vt, ushort* __restrict__ ut,
                                ushort* __restrict__ cb) {
  int idx = blockIdx.x * 256 + threadIdx.x;
  if (idx < VT_ELEMS) {
    int d = idx & (D_DIM - 1);
    int n = (idx >> 10) % N1;
    int l = idx / (N1 * D_DIM);
    float val = 0.f;
    if (n < 256) {
      int e = n >> 6, r = n & 63;
      val = V[(((l * E_NUM + e) * D_DIM) + d) * R_DIM + r];   // Vt[l][e*64+r][d] = V[l,e,d,r]
    } else if (n < 260) {
      val = gw[(n - 256) * D_DIM + d];                        // gating cols
    }
    vt[idx] = f2b(val);
  } else if (idx < VT_ELEMS + UT_ELEMS) {
    int i2 = idx - VT_ELEMS;
    int er = i2 & 255;
    int d = (i2 >> 8) & (D_DIM - 1);
    int l = i2 >> 18;
    int e = er >> 6, r = er & 63;
    ut[i2] = f2b(U[((l * E_NUM + e) * D_DIM + d) * R_DIM + r]);  // Ut[l][d][e*64+r]
  } else if (idx < PACK_TOTAL) {
    int i3 = idx - VT_ELEMS - UT_ELEMS;
    cb[i3] = f2b(C[i3]);   // C[l,e,r,s] already is Bt[n=r][k=s]
  }
}

// ---------------- fused 3-layer CrossNet: each block owns 32 rows end-to-end ----------------
// TPB=1024: 16 waves in one block -> 4 waves/SIMD (round-1 showed 4 waves/SIMD helps ONLY if
// per-work weight traffic is unchanged; this keeps round-0's BT=32 stream amortization).
// Per-thread f32 state halves vs round-0 (xlr 32 + acc3 32), fitting the 128-VGPR / 4-wave budget.
// Gating computed redundantly per wave (same bg rows for all waves -> L1 broadcast), softmax via
// intra-wave shuffles: balanced waves, no serial phase, no glog/gate LDS.

__global__ __launch_bounds__(TPB, 4) void crossnet_fused(
    const float* __restrict__ inputs, const float* __restrict__ bias,
    const ushort* __restrict__ Vt, const ushort* __restrict__ Ut,
    const ushort* __restrict__ Cb, float* __restrict__ out) {
  __shared__ ushort xl[BT * XL_STRIDE];    // x_l bf16, A-operand for GEMM1 (66048 B)
  __shared__ ushort x0s[BT * XL_STRIDE];   // x0 bf16 (66048 B)
  __shared__ ushort t1[BT * T1_STRIDE];    // v1, later w = gate*v2 (16896 B)

  const int tid = threadIdx.x;
  const int wave = tid >> 6;      // 0..15
  const int lane = tid & 63;
  const int l15 = lane & 15;
  const int quad = lane >> 4;
  const long rowbase = (long)blockIdx.x * BT;

  // ---- stage inputs -> xl, x0s (coalesced float4): 32 rows x 256 float4 ----
  #pragma unroll
  for (int i = 0; i < 8; ++i) {
    int idx = tid + i * TPB;       // float4 index within [32][256]
    int r = idx >> 8;
    int c4 = idx & 255;
    float4 v = ((const float4*)(inputs + (rowbase + r) * D_DIM))[c4];
    ushort4 h;
    h.x = f2b(v.x); h.y = f2b(v.y); h.z = f2b(v.z); h.w = f2b(v.w);
    *(ushort4*)&xl[r * XL_STRIDE + c4 * 4] = h;
    *(ushort4*)&x0s[r * XL_STRIDE + c4 * 4] = h;
  }

  // ---- x_l kept in f32 registers at this wave's GEMM2 C-layout positions ----
  // wave owns cols [wave*64, wave*64+64); lane holds rows m*16+quad*4+rg, col nt*16+l15
  float xlr[4][2][4];
  #pragma unroll
  for (int nt = 0; nt < 4; ++nt)
    #pragma unroll
    for (int m = 0; m < 2; ++m)
      #pragma unroll
      for (int rg = 0; rg < 4; ++rg) {
        int row = m * 16 + quad * 4 + rg;
        int col = wave * 64 + nt * 16 + l15;
        xlr[nt][m][rg] = inputs[(rowbase + row) * D_DIM + col];
      }
  __syncthreads();

  const f32x4 zf = {0.f, 0.f, 0.f, 0.f};
  const int eC = wave >> 2;   // expert this wave handles in phase C
  const int qh = wave & 3;    // which 16-col quarter of the 64 r-outputs

  for (int l = 0; l < L_NUM; ++l) {
    const ushort* vtl = Vt + l * N1 * D_DIM;
    const ushort* utl = Ut + l * D_DIM * 256;
    const ushort* cbl = Cb + l * E_NUM * R_DIM * R_DIM;

    // ========== Phase A: GEMM1  T1[32,256] = xl[32,1024] @ V  (+ redundant gating tile) ====
    f32x4 acc1[2];              // m = 0,1 (rows 0-15, 16-31), this wave's 16 V-cols
    acc1[0] = zf; acc1[1] = zf;
    f32x4 accg[2];              // gating logits tile, redundant per wave
    accg[0] = zf; accg[1] = zf;

    const ushort* xa0 = &xl[l15 * XL_STRIDE + quad * 8];
    const ushort* xa1 = &xl[(16 + l15) * XL_STRIDE + quad * 8];
    const ushort* vb0 = vtl + (wave * 16 + l15) * D_DIM + quad * 8;
    const ushort* vbg = vtl + (256 + l15) * D_DIM + quad * 8;
    #pragma unroll 4
    for (int k0 = 0; k0 < D_DIM; k0 += 32) {
      bf16x8 a0 = *(const bf16x8*)(xa0 + k0);
      bf16x8 a1 = *(const bf16x8*)(xa1 + k0);
      bf16x8 b0 = *(const bf16x8*)(vb0 + k0);
      bf16x8 bg = *(const bf16x8*)(vbg + k0);
      acc1[0] = MFMA16(a0, b0, acc1[0]);
      acc1[1] = MFMA16(a1, b0, acc1[1]);
      accg[0] = MFMA16(a0, bg, accg[0]);
      accg[1] = MFMA16(a1, bg, accg[1]);
    }

    // epilogue: v1 = tanh(T1) -> t1 (bf16)
    {
      int ncol = wave * 16 + l15;
      #pragma unroll
      for (int m = 0; m < 2; ++m)
        #pragma unroll
        for (int rg = 0; rg < 4; ++rg)
          t1[(m * 16 + quad * 4 + rg) * T1_STRIDE + ncol] = f2b(tanh_fast(acc1[m][rg]));
    }

    // in-register softmax over E=4 (lanes l15=0..3 of my quad hold the 4 logits per row)
    float gr[2][4];
    {
      const int qbase = lane & 48;
      #pragma unroll
      for (int m = 0; m < 2; ++m)
        #pragma unroll
        for (int rg = 0; rg < 4; ++rg) {
          float g0 = __shfl(accg[m][rg], qbase + 0);
          float g1 = __shfl(accg[m][rg], qbase + 1);
          float g2 = __shfl(accg[m][rg], qbase + 2);
          float g3 = __shfl(accg[m][rg], qbase + 3);
          float mx = fmaxf(fmaxf(g0, g1), fmaxf(g2, g3));
          float e0 = __expf(g0 - mx), e1 = __expf(g1 - mx);
          float e2 = __expf(g2 - mx), e3 = __expf(g3 - mx);
          float inv = 1.f / (e0 + e1 + e2 + e3);
          float ge = (eC == 0) ? e0 : (eC == 1) ? e1 : (eC == 2) ? e2 : e3;
          gr[m][rg] = ge * inv;
        }
    }
    __syncthreads();   // t1 (v1) ready for all waves

    // ========== Phase C: block-diag v2 = tanh(C @ v1), w = gate*v2 ==========
    f32x4 acc2[2];
    acc2[0] = zf; acc2[1] = zf;
    #pragma unroll
    for (int k0 = 0; k0 < 64; k0 += 32) {
      bf16x8 a0 = *(const bf16x8*)&t1[l15 * T1_STRIDE + eC * 64 + k0 + quad * 8];
      bf16x8 a1 = *(const bf16x8*)&t1[(16 + l15) * T1_STRIDE + eC * 64 + k0 + quad * 8];
      bf16x8 b0 = *(const bf16x8*)&cbl[(eC * 64 + qh * 16 + l15) * 64 + k0 + quad * 8];
      acc2[0] = MFMA16(a0, b0, acc2[0]);
      acc2[1] = MFMA16(a1, b0, acc2[1]);
    }
    __syncthreads();  // all v1 reads done -> safe to overwrite t1 with w
    {
      int ncol = eC * 64 + qh * 16 + l15;
      #pragma unroll
      for (int m = 0; m < 2; ++m)
        #pragma unroll
        for (int rg = 0; rg < 4; ++rg)
          t1[(m * 16 + quad * 4 + rg) * T1_STRIDE + ncol] = f2b(gr[m][rg] * tanh_fast(acc2[m][rg]));
    }
    __syncthreads();

    // ========== Phase D: GEMM2  S[32,1024] = w[32,256] @ Ut^T ==========
    f32x4 acc3[4][2];
    #pragma unroll
    for (int nt = 0; nt < 4; ++nt) { acc3[nt][0] = zf; acc3[nt][1] = zf; }
    const ushort* wa0 = &t1[l15 * T1_STRIDE + quad * 8];
    const ushort* wa1 = &t1[(16 + l15) * T1_STRIDE + quad * 8];
    const ushort* ub = utl + (wave * 64 + l15) * 256 + quad * 8;
    #pragma unroll 2
    for (int k0 = 0; k0 < 256; k0 += 32) {
      bf16x8 a0 = *(const bf16x8*)(wa0 + k0);
      bf16x8 a1 = *(const bf16x8*)(wa1 + k0);
      #pragma unroll
      for (int nt = 0; nt < 4; ++nt) {
        bf16x8 b = *(const bf16x8*)(ub + nt * 16 * 256 + k0);
        acc3[nt][0] = MFMA16(a0, b, acc3[nt][0]);
        acc3[nt][1] = MFMA16(a1, b, acc3[nt][1]);
      }
    }

    // epilogue: x_new = x_l + x0*(S + bias[l]); update f32 regs + bf16 LDS shadow
    #pragma unroll
    for (int nt = 0; nt < 4; ++nt) {
      int col = wave * 64 + nt * 16 + l15;
      float bv = bias[l * D_DIM + col];
      #pragma unroll
      for (int m = 0; m < 2; ++m)
        #pragma unroll
        for (int rg = 0; rg < 4; ++rg) {
          int row = m * 16 + quad * 4 + rg;
          float x0v = b2f(x0s[row * XL_STRIDE + col]);
          float xn = xlr[nt][m][rg] + x0v * (acc3[nt][m][rg] + bv);
          xlr[nt][m][rg] = xn;
          xl[row * XL_STRIDE + col] = f2b(xn);
        }
    }
    __syncthreads();  // xl/t1 safe for next layer
  }

  // ---- final store (f32 residual path, full precision) ----
  #pragma unroll
  for (int nt = 0; nt < 4; ++nt) {
    int col = wave * 64 + nt * 16 + l15;
    #pragma unroll
    for (int m = 0; m < 2; ++m)
      #pragma unroll
      for (int rg = 0; rg < 4; ++rg) {
        int row = m * 16 + quad * 4 + rg;
        out[(rowbase + row) * D_DIM + col] = xlr[nt][m][rg];
      }
  }
}

extern "C" void kernel_launch(void* const* d_in, const int* in_sizes, int n_in,
                              void* d_out, int out_size, void* d_ws, size_t ws_size,
                              hipStream_t stream) {
  (void)in_sizes; (void)n_in; (void)out_size; (void)ws_size;
  const float* inputs = (const float*)d_in[0];
  const float* U      = (const float*)d_in[1];
  const float* V      = (const float*)d_in[2];
  const float* C      = (const float*)d_in[3];
  const float* gw     = (const float*)d_in[4];
  const float* bias   = (const float*)d_in[5];
  float* out = (float*)d_out;

  ushort* vt = (ushort*)d_ws;          // 3*272*1024 bf16
  ushort* ut = vt + VT_ELEMS;          // 3*1024*256 bf16
  ushort* cb = ut + UT_ELEMS;          // 3*4*64*64  bf16

  pack_all_kernel<<<(PACK_TOTAL + 255) / 256, 256, 0, stream>>>(U, V, C, gw, vt, ut, cb);

  crossnet_fused<<<B_ROWS / BT, TPB, 0, stream>>>(inputs, bias, vt, ut, cb, out);
}